// Round 5
// baseline (735.365 us; speedup 1.0000x reference)
//
#include <hip/hip_runtime.h>

// VQ nearest-codebook: N=262144 rows x D=64, K=1024 codes.
// Numerics contract (bit-exact vs np f32 reference, verified in prior session):
//   dist_k = fl32( fl32(zsq - 2*dot_k) + cbsq_k ), argmin -> lowest index wins.
//   dot_k MUST be one sequential fmaf chain d=0..63 per row. DO NOT re-associate.
//   zsq/cbsq: f64-accumulate then round once. (2*s is exact; fp-contract of
//   zsq-2*s to fma(-2,s,zsq) is value-identical.)
//
// R8 change: R=1 row/thread -> 4 waves/SIMD (was 2), same SMEM pipeline.
//   Rationale (R7 counters): scalarization WORKED (LDS 0, VGPR 128->88,
//   520us) but VALUBusy fell to 51% -- wall 1220 cyc/row/CU vs 552 issue.
//   The two lgkmcnt(0) drains/row have ~240 cyc wall distance at 2 waves/SIMD
//   vs ~400-500 cyc scalar-L2 latency (codebook streams through 16KB sK$;
//   lead wave misses). Full-row double-buffer is impossible (128 SGPR > ~102
//   file) -> the fix is wave count: total waves = N/(64*R), so R=1 gives
//   4 waves/SIMD: ~2x drain distance AND 4-way stall coverage. VGPR ~84
//   (q 64 + temps) < 128 cap @ 4 waves/SIMD. sK$ temporal locality: 16
//   waves/CU walk the same k sequence, only the lead wave pays L2.
//   Perfect-hiding floor rises 552->~640 cyc/row/CU (overhead duplicated
//   across 2x waves) -- acceptable vs the 668-cyc stall we're buying back.
//   NO per-thread arrays anywhere (scratch hazard) -- all named values.

#define VQ_D 64
#define VQ_MAXK 1024

typedef __attribute__((ext_vector_type(4))) float f4;
typedef const __attribute__((address_space(4))) f4* cb4c_t;
typedef const __attribute__((address_space(4))) float* fc_t;

// Single-row sequential fused-FMA chain step over one float4-worth of c
// (ascending d; ONE chain -> do not reorder). c is an SGPR-resident f4.
#define VQ_CH1(q, c) do { \
    s0 = fmaf((q).x, (c).x, s0); \
    s0 = fmaf((q).y, (c).y, s0); \
    s0 = fmaf((q).z, (c).z, s0); \
    s0 = fmaf((q).w, (c).w, s0); } while (0)

// f64 sum-of-squares over one float4 (order-free: tie-invariant).
#define VQ_SQ(acc, q) do { \
    (acc) += (double)(q).x * (double)(q).x; \
    (acc) += (double)(q).y * (double)(q).y; \
    (acc) += (double)(q).z * (double)(q).z; \
    (acc) += (double)(q).w * (double)(q).w; } while (0)

#define SBAR() __builtin_amdgcn_sched_barrier(0)

// kernel1: cbsq[k] = fl32(sum_d f64(cb[k][d]^2)). Same numerics as the old
// in-block prologue (f64 accumulate, round once).
__global__ void vq_cbsq_kernel(const float* __restrict__ cb,
                               float* __restrict__ cbsq, int K)
{
    const int k = blockIdx.x * blockDim.x + threadIdx.x;
    if (k >= K) return;
    const float* c = cb + (size_t)k * VQ_D;
    double s = 0.0;
    #pragma unroll
    for (int d = 0; d < VQ_D; ++d) { double v = (double)c[d]; s += v * v; }
    cbsq[k] = (float)s;
}

template <bool USE_WS>
__global__ __launch_bounds__(256, 4) void vq_argmin_kernel(
    const float* __restrict__ z_e,
    const float* __restrict__ cb,
    const float* __restrict__ cbsq_ws,   // valid iff USE_WS
    float* __restrict__ out,             // [N*D] z_q, then [N] indices (as float)
    int N, int K)
{
    __shared__ float s_cbsq[VQ_MAXK];    // used only if !USE_WS

    if (!USE_WS) {
        for (int k = threadIdx.x; k < K; k += blockDim.x) {
            const float* c = cb + (size_t)k * VQ_D;
            double s = 0.0;
            #pragma unroll
            for (int d = 0; d < VQ_D; ++d) { double v = (double)c[d]; s += v * v; }
            s_cbsq[k] = (float)s;
        }
        __syncthreads();
    }

    const int n = blockIdx.x * blockDim.x + threadIdx.x;
    if (n >= N) return;                  // after the (optional) barrier: legal

    // z row in 16 NAMED float4 registers (NOT an array — scratch hazard).
    const float4* zp = (const float4*)(z_e + (size_t)n * VQ_D);
    float4 q0  = zp[0],  q1  = zp[1],  q2  = zp[2],  q3  = zp[3];
    float4 q4  = zp[4],  q5  = zp[5],  q6  = zp[6],  q7  = zp[7];
    float4 q8  = zp[8],  q9  = zp[9],  q10 = zp[10], q11 = zp[11];
    float4 q12 = zp[12], q13 = zp[13], q14 = zp[14], q15 = zp[15];

    // ||z||^2 in f64, rounded once.
    double zs0 = 0.0;
    VQ_SQ(zs0, q0);  VQ_SQ(zs0, q1);  VQ_SQ(zs0, q2);  VQ_SQ(zs0, q3);
    VQ_SQ(zs0, q4);  VQ_SQ(zs0, q5);  VQ_SQ(zs0, q6);  VQ_SQ(zs0, q7);
    VQ_SQ(zs0, q8);  VQ_SQ(zs0, q9);  VQ_SQ(zs0, q10); VQ_SQ(zs0, q11);
    VQ_SQ(zs0, q12); VQ_SQ(zs0, q13); VQ_SQ(zs0, q14); VQ_SQ(zs0, q15);
    const float zsq = (float)zs0;

    // Constant-AS views -> uniform loads become s_load (SGPR-resident rows).
    cb4c_t cbc = (cb4c_t)(unsigned long long)cb;      // 16 f4 per row
    fc_t   sqc = (fc_t)(unsigned long long)cbsq_ws;

    float best = 3.4e38f;
    int bestk = 0;

    // Half-row ping-pong buffers (SGPR f4s). X = d0..31, Y = d32..63.
    f4 X0, X1, X2, X3, X4, X5, X6, X7;
    f4 Y0, Y1, Y2, Y3, Y4, Y5, Y6, Y7;
    float cq;

    // Prologue: issue A(0) into X. (One-time short-distance wait at k=0.)
    X0 = cbc[0]; X1 = cbc[1]; X2 = cbc[2]; X3 = cbc[3];
    X4 = cbc[4]; X5 = cbc[5]; X6 = cbc[6]; X7 = cbc[7];

    #pragma unroll 1
    for (int k = 0; k < K; ++k) {
        const int kb = k << 4;
        float s0 = 0.f;

        // First X use: lgkmcnt(0) lands HERE, draining X issued mid-B-block
        // of the previous iteration.
        VQ_CH1(q0, X0);
        SBAR();
        // Issue box: B(k) -> Y, plus cbsq(k). Boxed so the scheduler can
        // neither hoist these above the X-wait nor sink them toward their use.
        Y0 = cbc[kb + 8];  Y1 = cbc[kb + 9];  Y2 = cbc[kb + 10]; Y3 = cbc[kb + 11];
        Y4 = cbc[kb + 12]; Y5 = cbc[kb + 13]; Y6 = cbc[kb + 14]; Y7 = cbc[kb + 15];
        cq = USE_WS ? sqc[k] : s_cbsq[k];
        SBAR();
        // Rest of A-half (d4..31), sequential ascending d.
        VQ_CH1(q1, X1); VQ_CH1(q2, X2); VQ_CH1(q3, X3);
        VQ_CH1(q4, X4); VQ_CH1(q5, X5); VQ_CH1(q6, X6); VQ_CH1(q7, X7);

        // First Y use: lgkmcnt(0) lands HERE, draining Y+cq.
        VQ_CH1(q8, Y0);
        SBAR();
        // Issue box: A(k+1) -> X (clamped last iter; 64B reload, harmless).
        {
            int nk = k + 1; if (nk >= K) nk = K - 1;
            const int nb = nk << 4;
            X0 = cbc[nb + 0]; X1 = cbc[nb + 1]; X2 = cbc[nb + 2]; X3 = cbc[nb + 3];
            X4 = cbc[nb + 4]; X5 = cbc[nb + 5]; X6 = cbc[nb + 6]; X7 = cbc[nb + 7];
        }
        SBAR();
        // Rest of B-half (d36..63), sequential ascending d.
        VQ_CH1(q9,  Y1); VQ_CH1(q10, Y2); VQ_CH1(q11, Y3);
        VQ_CH1(q12, Y4); VQ_CH1(q13, Y5); VQ_CH1(q14, Y6); VQ_CH1(q15, Y7);

        // cq completed at the Y-wait; no further lgkm wait needed here.
        const float u    = zsq - 2.0f * s0;   // 2*s exact; one fp32 round
        const float dist = u + cq;            // fp32 round, as reference
        if (dist < best) { best = dist; bestk = k; }  // strict <: lowest k
    }

    // z_q gather (divergent index -> per-lane VMEM; codebook L2-resident).
    const float4* cq4 = (const float4*)(cb + (size_t)bestk * VQ_D);
    float4* oq = (float4*)(out + (size_t)n * VQ_D);
    #pragma unroll
    for (int i = 0; i < VQ_D / 4; ++i) oq[i] = cq4[i];

    // Index as float (exact for k < 2^24).
    out[(size_t)N * VQ_D + n] = (float)bestk;
}

extern "C" void kernel_launch(void* const* d_in, const int* in_sizes, int n_in,
                              void* d_out, int out_size, void* d_ws, size_t ws_size,
                              hipStream_t stream) {
    const float* z_e = (const float*)d_in[0];
    const float* cb  = (const float*)d_in[1];
    float* out = (float*)d_out;

    const int N = in_sizes[0] / VQ_D;
    const int K = in_sizes[1] / VQ_D;

    const int block = 256;
    const int grid = (N + block - 1) / block;

    const bool use_ws = (d_ws != nullptr) && (ws_size >= (size_t)K * sizeof(float));
    if (use_ws) {
        float* cbsq = (float*)d_ws;
        vq_cbsq_kernel<<<(K + 255) / 256, 256, 0, stream>>>(cb, cbsq, K);
        vq_argmin_kernel<true><<<grid, block, 0, stream>>>(z_e, cb, cbsq, out, N, K);
    } else {
        vq_argmin_kernel<false><<<grid, block, 0, stream>>>(z_e, cb, nullptr, out, N, K);
    }
}